// Round 8
// baseline (210.130 us; speedup 1.0000x reference)
//
#include <hip/hip_runtime.h>
#include <hip/hip_cooperative_groups.h>
#include <math.h>

namespace cg = cooperative_groups;

#define BB 16
#define TT 4096
#define EE 1024
#define HALF 2048
#define WIN 15
#define EPSF 1e-6f
#define PI_F   3.14159265358979323846f
#define PIO2_F 1.57079632679489662f

// Branchless cephes-style asin: ~16 VALU ops, 1 sqrt, no divergence.
__device__ __forceinline__ float fast_asinf(float v) {
    float a  = fabsf(v);
    float z1 = a * a;
    float z2 = 0.5f * (1.0f - a);
    bool big = a > 0.5f;
    float z = big ? z2 : z1;
    float s = big ? sqrtf(z) : a;
    float p = fmaf(z, 4.2163199048e-2f, 2.4181311049e-2f);
    p = fmaf(z, p, 4.5470025998e-2f);
    p = fmaf(z, p, 7.4953002686e-2f);
    p = fmaf(z, p, 1.6666752422e-1f);
    float r = fmaf(s * z, p, s);
    float rb = fmaf(-2.0f, r, PIO2_F);
    r = big ? rb : r;
    return copysignf(r, v);
}

// ---------------------------------------------------------------------------
// Phase kernel (unchanged from R7): wave per row, b-major outputs.
// ---------------------------------------------------------------------------
__global__ void phase_kernel(const float* __restrict__ x,
                             const float* __restrict__ taper,
                             float* __restrict__ phases_b,
                             float* __restrict__ c0_b) {
    const int wave = threadIdx.x >> 6;
    const int lane = threadIdx.x & 63;
    const int row  = blockIdx.x * 4 + wave;      // [0, B*T)
    const int b = row >> 12;
    const int t = row & (TT - 1);
    const float tap = taper[t];
    const float* xr = x + (size_t)row * EE;

    const float c0 = xr[0] * tap;
    const float r = fabsf(c0) + EPSF;
    const float scale = tap / r;
    const float start = (c0 >= 0.0f) ? 0.0f : PI_F;
    const float LO = -1.0f + EPSF, HI = 1.0f - EPSF;

    const float4* xr4 = (const float4*)xr;
    float sum = 0.0f;
    #pragma unroll
    for (int j = 0; j < 4; ++j) {
        float4 v = xr4[j * 64 + lane];
        float a0 = fast_asinf(fminf(fmaxf(v.x * scale, LO), HI));
        if ((j | lane) == 0) a0 = 0.0f;          // element 0 excluded
        sum += a0;
        sum += fast_asinf(fminf(fmaxf(v.y * scale, LO), HI));
        sum += fast_asinf(fminf(fmaxf(v.z * scale, LO), HI));
        sum += fast_asinf(fminf(fmaxf(v.w * scale, LO), HI));
    }
    #pragma unroll
    for (int off = 32; off > 0; off >>= 1)
        sum += __shfl_xor(sum, off, 64);

    if (lane == 0) {
        phases_b[b * TT + t] = start + sum;
        c0_b[b * TT + t]     = c0;
    }
}

// ---------------------------------------------------------------------------
// Stage: tdiff (b-major). Grid has >= 65536 threads; extra threads idle.
// ---------------------------------------------------------------------------
__device__ __forceinline__ void stage_tdiff(const float* __restrict__ c0_b,
                                            float* __restrict__ tdiff_b) {
    const int f = blockIdx.x * blockDim.x + threadIdx.x;   // b*TT + t
    if (f < BB * TT) {
        const int t = f & (TT - 1);
        float num = 0.0f;
        #pragma unroll
        for (int d = 1; d <= WIN; ++d) {
            if (d <= t) num += (float)d * c0_b[f - d];
        }
        const int s = (t < WIN) ? t : WIN;
        const float norm = 0.5f * (float)s * (float)(s + 1);
        tdiff_b[f] = (norm > 0.0f) ? (num / norm) : 0.0f;
    }
}

// ---------------------------------------------------------------------------
// Stage: GEMM (R7 structure, verbatim): A b-major [16][K], LDS-staged tile,
// coalesced float4 weight stream, contiguous ds_read_b128, no gathers.
// 512 blocks: 8 cols/block, 2 problems. MODE 0: silu->H_b. MODE 1: tanh->out.
// ---------------------------------------------------------------------------
__device__ __forceinline__ void gld_lds16(const float* g, float* l) {
    __builtin_amdgcn_global_load_lds(
        (const __attribute__((address_space(1))) unsigned int*)g,
        (__attribute__((address_space(3))) unsigned int*)l,
        16, 0, 0);
}

#define KT_G 1024
#define LROW (KT_G + 4)

template <int K, int MODE>
__device__ __forceinline__ void stage_gemm(const float* __restrict__ A0,
                                           const float* __restrict__ W0,
                                           const float* __restrict__ bias0,
                                           float* out0,
                                           const float* __restrict__ A1,
                                           const float* __restrict__ W1,
                                           const float* __restrict__ bias1,
                                           float* out1,
                                           float* als) {
    constexpr int NT = K / KT_G;

    const int nb = HALF / 8;                      // 256 blocks per problem
    const int g = blockIdx.x / nb;
    const int obase = (blockIdx.x % nb) * 8;

    const float* A    = g ? A1 : A0;
    const float* W    = g ? W1 : W0;
    const float* bias = g ? bias1 : bias0;
    float* out        = g ? out1 : out0;

    const int wv   = threadIdx.x >> 6;            // 0..3
    const int lane = threadIdx.x & 63;
    const int col0 = obase + wv * 2;
    const int col1 = col0 + 1;
    const float* w0p = W + (size_t)col0 * K;
    const float* w1p = W + (size_t)col1 * K;

    float acc0[16], acc1[16];
    #pragma unroll
    for (int i = 0; i < 16; ++i) { acc0[i] = 0.0f; acc1[i] = 0.0f; }

    for (int t = 0; t < NT; ++t) {
        __syncthreads();                          // als free
        #pragma unroll
        for (int i = 0; i < 4; ++i) {
            const int b = wv * 4 + i;
            const float* src = A + (size_t)b * K + t * KT_G + lane * 4;
            float* dst = &als[b * LROW];
            #pragma unroll
            for (int q = 0; q < 4; ++q)
                gld_lds16(src + q * 256, dst + q * 256);
        }
        __syncthreads();                          // drain -> tile ready

        float4 w0[4], w1[4];
        #pragma unroll
        for (int s = 0; s < 4; ++s) {
            w0[s] = *(const float4*)(w0p + t * KT_G + s * 256 + lane * 4);
            w1[s] = *(const float4*)(w1p + t * KT_G + s * 256 + lane * 4);
        }

        #pragma unroll
        for (int s = 0; s < 4; ++s) {
            #pragma unroll
            for (int b = 0; b < 16; ++b) {
                const float4 a4 = *(const float4*)&als[b * LROW + s * 256 + lane * 4];
                acc0[b] += w0[s].x*a4.x + w0[s].y*a4.y + w0[s].z*a4.z + w0[s].w*a4.w;
                acc1[b] += w1[s].x*a4.x + w1[s].y*a4.y + w1[s].z*a4.z + w1[s].w*a4.w;
            }
        }
    }

    #pragma unroll
    for (int off = 32; off > 0; off >>= 1) {
        #pragma unroll
        for (int i = 0; i < 16; ++i) {
            acc0[i] += __shfl_xor(acc0[i], off, 64);
            acc1[i] += __shfl_xor(acc1[i], off, 64);
        }
    }

    const bool isw0 = (lane == 0), isw1 = (lane == 32);
    if (isw0 || isw1) {
        const int o = isw0 ? col0 : col1;
        const float bs = bias[o];
        #pragma unroll
        for (int i = 0; i < 16; ++i) {
            float s = (isw0 ? acc0[i] : acc1[i]) + bs;
            if (MODE == 0) {
                s = s / (1.0f + expf(-s));        // silu
                out[(size_t)i * HALF + o] = s;    // H b-major [16][HALF]
            } else {
                s = tanhf(s);
                out[(size_t)i * (HALF * 2) + o * 2 + g] = s;
            }
        }
    }
    __syncthreads();
}

// ---------------------------------------------------------------------------
// Cooperative mega-kernel: tdiff -> sync -> GEMM1 -> sync -> GEMM2.
// 512 blocks x 256 threads = exactly 2 blocks/CU co-resident (66 KiB LDS).
// ---------------------------------------------------------------------------
__global__ void __launch_bounds__(256)
mega_kernel(const float* phases_b, const float* c0_b, float* tdiff_b,
            const float* cW1, const float* cb1, const float* cW2, const float* cb2,
            const float* pW1, const float* pb1, const float* pW2, const float* pb2,
            float* H1_b, float* H2_b, float* out) {
    __shared__ float als[16 * LROW];
    cg::grid_group grid = cg::this_grid();

    stage_tdiff(c0_b, tdiff_b);
    grid.sync();
    stage_gemm<TT, 0>(phases_b, cW1, cb1, H1_b, tdiff_b, pW1, pb1, H2_b, als);
    grid.sync();
    stage_gemm<HALF, 1>(H1_b, cW2, cb2, out, H2_b, pW2, pb2, out, als);
}

// Fallback separate kernels (same device code).
__global__ void __launch_bounds__(256)
k_tdiff(const float* c0_b, float* tdiff_b) { stage_tdiff(c0_b, tdiff_b); }

template <int K, int MODE>
__global__ void __launch_bounds__(256)
k_gemm(const float* A0, const float* W0, const float* b0, float* o0,
       const float* A1, const float* W1, const float* b1, float* o1) {
    __shared__ float als[16 * LROW];
    stage_gemm<K, MODE>(A0, W0, b0, o0, A1, W1, b1, o1, als);
}

extern "C" void kernel_launch(void* const* d_in, const int* in_sizes, int n_in,
                              void* d_out, int out_size, void* d_ws, size_t ws_size,
                              hipStream_t stream) {
    const float* x     = (const float*)d_in[0];
    const float* taper = (const float*)d_in[1];
    const float* cW1   = (const float*)d_in[2];
    const float* cb1   = (const float*)d_in[3];
    const float* cW2   = (const float*)d_in[4];
    const float* cb2   = (const float*)d_in[5];
    const float* pW1   = (const float*)d_in[6];
    const float* pb1   = (const float*)d_in[7];
    const float* pW2   = (const float*)d_in[8];
    const float* pb2   = (const float*)d_in[9];
    float* out = (float*)d_out;
    float* ws  = (float*)d_ws;

    float* phases_b = ws;                         // [16][4096]
    float* c0_b     = ws + 65536;                 // [16][4096]
    float* tdiff_b  = ws + 131072;                // [16][4096]
    float* H1_b     = ws + 196608;                // [16][2048]
    float* H2_b     = ws + 229376;                // [16][2048]

    phase_kernel<<<BB * TT / 4, 256, 0, stream>>>(x, taper, phases_b, c0_b);

    void* args[] = {
        (void*)&phases_b, (void*)&c0_b, (void*)&tdiff_b,
        (void*)&cW1, (void*)&cb1, (void*)&cW2, (void*)&cb2,
        (void*)&pW1, (void*)&pb1, (void*)&pW2, (void*)&pb2,
        (void*)&H1_b, (void*)&H2_b, (void*)&out,
    };
    hipError_t e = hipLaunchCooperativeKernel((const void*)mega_kernel,
                                              dim3(512), dim3(256), args, 0, stream);
    if (e != hipSuccess) {
        (void)hipGetLastError();                  // clear, use fallback path
        k_tdiff<<<256, 256, 0, stream>>>(c0_b, tdiff_b);
        k_gemm<TT, 0><<<512, 256, 0, stream>>>(phases_b, cW1, cb1, H1_b,
                                               tdiff_b, pW1, pb1, H2_b);
        k_gemm<HALF, 1><<<512, 256, 0, stream>>>(H1_b, cW2, cb2, out,
                                                 H2_b, pW2, pb2, out);
    }
}

// Round 9
// 108.967 us; speedup vs baseline: 1.9284x; 1.9284x over previous
//
#include <hip/hip_runtime.h>
#include <math.h>

#define BB 16
#define TT 4096
#define EE 1024
#define HALF 2048
#define WIN 15
#define EPSF 1e-6f
#define PI_F   3.14159265358979323846f
#define PIO2_F 1.57079632679489662f

// Branchless cephes-style asin: ~16 VALU ops, 1 sqrt, no divergence.
__device__ __forceinline__ float fast_asinf(float v) {
    float a  = fabsf(v);
    float z1 = a * a;
    float z2 = 0.5f * (1.0f - a);
    bool big = a > 0.5f;
    float z = big ? z2 : z1;
    float s = big ? sqrtf(z) : a;
    float p = fmaf(z, 4.2163199048e-2f, 2.4181311049e-2f);
    p = fmaf(z, p, 4.5470025998e-2f);
    p = fmaf(z, p, 7.4953002686e-2f);
    p = fmaf(z, p, 1.6666752422e-1f);
    float r = fmaf(s * z, p, s);
    float rb = fmaf(-2.0f, r, PIO2_F);
    r = big ? rb : r;
    return copysignf(r, v);
}

// ---------------------------------------------------------------------------
// Phase + fused tdiff. Wave per row, b-major outputs.
// tdiff[t] = (sum d*c0[t-d]) / (s(s+1)/2) recomputed from x directly:
// lanes 1..15 each fetch x[b][t-d][0] (L1/L2-hot lines), 16-group butterfly.
// ---------------------------------------------------------------------------
__global__ void phase_tdiff_kernel(const float* __restrict__ x,
                                   const float* __restrict__ taper,
                                   float* __restrict__ phases_b,
                                   float* __restrict__ tdiff_b) {
    const int wave = threadIdx.x >> 6;
    const int lane = threadIdx.x & 63;
    const int row  = blockIdx.x * 4 + wave;      // [0, B*T); 4 consecutive t, same b
    const int b = row >> 12;
    const int t = row & (TT - 1);
    const float tap = taper[t];
    const float* xr = x + (size_t)row * EE;

    // issue tdiff gather early so its latency hides under the asin loop
    float xd = 0.0f, tapd = 0.0f;
    const int td = t - lane;
    const bool do_d = (lane >= 1) && (lane <= WIN) && (lane <= t);
    if (do_d) {
        xd   = x[((size_t)b * TT + td) * EE];    // element 0 of row t-lane
        tapd = taper[td];
    }

    const float c0 = xr[0] * tap;
    const float r = fabsf(c0) + EPSF;
    const float scale = tap / r;
    const float start = (c0 >= 0.0f) ? 0.0f : PI_F;
    const float LO = -1.0f + EPSF, HI = 1.0f - EPSF;

    const float4* xr4 = (const float4*)xr;
    float sum = 0.0f;
    #pragma unroll
    for (int j = 0; j < 4; ++j) {
        float4 v = xr4[j * 64 + lane];
        float a0 = fast_asinf(fminf(fmaxf(v.x * scale, LO), HI));
        if ((j | lane) == 0) a0 = 0.0f;          // element 0 excluded
        sum += a0;
        sum += fast_asinf(fminf(fmaxf(v.y * scale, LO), HI));
        sum += fast_asinf(fminf(fmaxf(v.z * scale, LO), HI));
        sum += fast_asinf(fminf(fmaxf(v.w * scale, LO), HI));
    }
    #pragma unroll
    for (int off = 32; off > 0; off >>= 1)
        sum += __shfl_xor(sum, off, 64);

    // tdiff numerator: sum over lanes 1..15 of d * x[b][t-d][0] * taper[t-d]
    float contrib = do_d ? ((float)lane * xd * tapd) : 0.0f;
    #pragma unroll
    for (int off = 8; off > 0; off >>= 1)
        contrib += __shfl_xor(contrib, off, 64); // sums within each 16-lane group

    if (lane == 0) {
        phases_b[b * TT + t] = start + sum;
        const int s = (t < WIN) ? t : WIN;
        const float norm = 0.5f * (float)s * (float)(s + 1);
        tdiff_b[b * TT + t] = (norm > 0.0f) ? (contrib / norm) : 0.0f;
    }
}

// ---------------------------------------------------------------------------
// GEMM (M=16): A b-major [16][K]. 2-deep pipelined LDS staging with counted
// vmcnt (no full drain in the main loop). KT=512, double-buffered (2x33KB,
// 2 blocks/CU). Per block: 8 output cols (2/wave). Weights stream coalesced
// float4 from HBM; A staged via global_load_lds, read as contiguous
// ds_read_b128 (conflict-free).
// MODE 0: silu -> H_b[b*HALF + o].  MODE 1: tanh -> out[b*4096 + o*2 + g].
// ---------------------------------------------------------------------------
__device__ __forceinline__ void gld_lds16(const float* g, float* l) {
    __builtin_amdgcn_global_load_lds(
        (const __attribute__((address_space(1))) unsigned int*)g,
        (__attribute__((address_space(3))) unsigned int*)l,
        16, 0, 0);
}

template <int K, int MODE>
__global__ void __launch_bounds__(256)
gemm_kernel(const float* __restrict__ A0, const float* __restrict__ W0,
            const float* __restrict__ bias0, float* __restrict__ out0,
            const float* __restrict__ A1, const float* __restrict__ W1,
            const float* __restrict__ bias1, float* __restrict__ out1) {
    constexpr int KT = 512;
    constexpr int NT = K / KT;
    constexpr int LROW = KT + 4;                  // 2064 B row stride (16B-aligned)
    __shared__ float als[2][16 * LROW];           // 2 x 33 KB

    const int nb = HALF / 8;                      // 256 blocks per problem
    const int g = blockIdx.x / nb;
    const int obase = (blockIdx.x % nb) * 8;

    const float* A    = g ? A1 : A0;
    const float* W    = g ? W1 : W0;
    const float* bias = g ? bias1 : bias0;
    float* out        = g ? out1 : out0;

    const int wv   = threadIdx.x >> 6;            // 0..3
    const int lane = threadIdx.x & 63;
    const int col0 = obase + wv * 2;
    const int col1 = col0 + 1;
    const float* w0p = W + (size_t)col0 * K;
    const float* w1p = W + (size_t)col1 * K;

    // stage tile t into buffer s: wave wv stages rows wv*4..wv*4+3,
    // 2 chunks of 256 floats per row -> 8 vmem ops per lane, in order.
    auto stage = [&](int t, int s) {
        #pragma unroll
        for (int i = 0; i < 4; ++i) {
            const int br = wv * 4 + i;
            const float* src = A + (size_t)br * K + t * KT + lane * 4;
            float* dst = &als[s][br * LROW];      // uniform base; HW adds lane*16B
            gld_lds16(src, dst);
            gld_lds16(src + 256, dst + 256);
        }
    };

    float acc0[16], acc1[16];
    #pragma unroll
    for (int i = 0; i < 16; ++i) { acc0[i] = 0.0f; acc1[i] = 0.0f; }

    stage(0, 0);                                  // 8 ops outstanding

    for (int t = 0; t < NT; ++t) {
        const int cur = t & 1;

        // weights for this tile: 4 coalesced float4 loads
        float4 w0v[2], w1v[2];
        #pragma unroll
        for (int s2 = 0; s2 < 2; ++s2) {
            w0v[s2] = *(const float4*)(w0p + t * KT + s2 * 256 + lane * 4);
            w1v[s2] = *(const float4*)(w1p + t * KT + s2 * 256 + lane * 4);
        }

        if (t + 1 < NT) {
            stage(t + 1, cur ^ 1);                // prefetch next tile (8 newest ops)
            // stage(t)'s 8 ops are the OLDEST in the queue; vmcnt retires
            // in order, so <=8 outstanding => stage(t) fully landed in LDS.
            asm volatile("s_waitcnt vmcnt(8)" ::: "memory");
        } else {
            asm volatile("s_waitcnt vmcnt(0)" ::: "memory");
        }
        __builtin_amdgcn_s_barrier();             // all waves: tile t staged
        __builtin_amdgcn_sched_barrier(0);        // no ds_read hoisting above

        #pragma unroll
        for (int s2 = 0; s2 < 2; ++s2) {
            #pragma unroll
            for (int br = 0; br < 16; ++br) {
                const float4 a4 = *(const float4*)&als[cur][br * LROW + s2 * 256 + lane * 4];
                acc0[br] += w0v[s2].x*a4.x + w0v[s2].y*a4.y + w0v[s2].z*a4.z + w0v[s2].w*a4.w;
                acc1[br] += w1v[s2].x*a4.x + w1v[s2].y*a4.y + w1v[s2].z*a4.z + w1v[s2].w*a4.w;
            }
        }
        __builtin_amdgcn_sched_barrier(0);        // reads done before barrier
        __builtin_amdgcn_s_barrier();             // safe to overwrite als[cur] next iter
    }

    // full-wave butterfly: every lane ends with complete sums
    #pragma unroll
    for (int off = 32; off > 0; off >>= 1) {
        #pragma unroll
        for (int i = 0; i < 16; ++i) {
            acc0[i] += __shfl_xor(acc0[i], off, 64);
            acc1[i] += __shfl_xor(acc1[i], off, 64);
        }
    }

    const bool isw0 = (lane == 0), isw1 = (lane == 32);
    if (isw0 || isw1) {
        const int o = isw0 ? col0 : col1;
        const float bs = bias[o];
        #pragma unroll
        for (int i = 0; i < 16; ++i) {
            float s = (isw0 ? acc0[i] : acc1[i]) + bs;
            if (MODE == 0) {
                s = s / (1.0f + expf(-s));        // silu
                out[(size_t)i * HALF + o] = s;    // H b-major [16][HALF]
            } else {
                s = tanhf(s);
                out[(size_t)i * (HALF * 2) + o * 2 + g] = s;
            }
        }
    }
}

extern "C" void kernel_launch(void* const* d_in, const int* in_sizes, int n_in,
                              void* d_out, int out_size, void* d_ws, size_t ws_size,
                              hipStream_t stream) {
    const float* x     = (const float*)d_in[0];
    const float* taper = (const float*)d_in[1];
    const float* cW1   = (const float*)d_in[2];
    const float* cb1   = (const float*)d_in[3];
    const float* cW2   = (const float*)d_in[4];
    const float* cb2   = (const float*)d_in[5];
    const float* pW1   = (const float*)d_in[6];
    const float* pb1   = (const float*)d_in[7];
    const float* pW2   = (const float*)d_in[8];
    const float* pb2   = (const float*)d_in[9];
    float* out = (float*)d_out;
    float* ws  = (float*)d_ws;

    float* phases_b = ws;                         // [16][4096]
    float* tdiff_b  = ws + 65536;                 // [16][4096]
    float* H1_b     = ws + 131072;                // [16][2048]
    float* H2_b     = ws + 163840;                // [16][2048]

    phase_tdiff_kernel<<<BB * TT / 4, 256, 0, stream>>>(x, taper, phases_b, tdiff_b);
    gemm_kernel<TT, 0><<<512, 256, 0, stream>>>(phases_b, cW1, cb1, H1_b,
                                                tdiff_b, pW1, pb1, H2_b);
    gemm_kernel<HALF, 1><<<512, 256, 0, stream>>>(H1_b, cW2, cb2, out,
                                                  H2_b, pW2, pb2, out);
}